// Round 9
// baseline (951.524 us; speedup 1.0000x reference)
//
#include <hip/hip_runtime.h>

#define NN 100000
#define NE 1200000
#define DD 64
#define EDIM 16
#define NL 3
#define NG 512
#define NC 10
#define NB_SCAN ((NN + 255) / 256)   // 391

typedef _Float16 f16x2 __attribute__((ext_vector_type(2)));
typedef _Float16 v8h   __attribute__((ext_vector_type(8)));
typedef float    v4f   __attribute__((ext_vector_type(4)));

__device__ __forceinline__ unsigned packh2(float a, float b) {
    f16x2 v; v[0] = (_Float16)a; v[1] = (_Float16)b;
    unsigned u; __builtin_memcpy(&u, &v, 4); return u;
}
__device__ __forceinline__ float dot2f(unsigned a, unsigned b, float c) {
    f16x2 av, bv;
    __builtin_memcpy(&av, &a, 4); __builtin_memcpy(&bv, &b, 4);
#if __has_builtin(__builtin_amdgcn_fdot2)
    return __builtin_amdgcn_fdot2(av, bv, c, false);
#else
    return c + (float)av[0]*(float)bv[0] + (float)av[1]*(float)bv[1];
#endif
}

// ---------------------------------------------------------------------------
// prep: Wc[l] = w_edge @ lin_w[l] (16x64) packed to f16 pairs per column;
//       bc[l] = b_edge @ lin_w[l] + lin_b[l]  (fp32)
__global__ __launch_bounds__(1024) void prep_kernel(
    const float* __restrict__ w_edge, const float* __restrict__ b_edge,
    const float* __restrict__ lin_w, const float* __restrict__ lin_b,
    unsigned* __restrict__ Wc16, float* __restrict__ bc)
{
    __shared__ float sWc[1024];
    const int l = blockIdx.x;
    const int tid = threadIdx.x;
    const float* Lw = lin_w + l * 4096;
    const int k = tid >> 6, col = tid & 63;
    float acc = 0.f;
    for (int j = 0; j < 64; ++j) acc = fmaf(w_edge[k*64 + j], Lw[j*64 + col], acc);
    sWc[k*64 + col] = acc;
    if (tid < 64) {
        float a = lin_b[l*64 + tid];
        for (int j = 0; j < 64; ++j) a = fmaf(b_edge[j], Lw[j*64 + tid], a);
        bc[l*64 + tid] = a;
    }
    __syncthreads();
    if (tid < 512) {
        const int j = tid >> 6, c = tid & 63;     // j = pair index (dims 2j,2j+1)
        Wc16[l*512 + j*64 + c] = packh2(sWc[(2*j)*64 + c], sWc[(2*j+1)*64 + c]);
    }
}

// ---------------------------------------------------------------------------
// pack node-GEMM weights [64x64] fp32 -> f16 MFMA B-fragment order.
// m: 0 = w_node, 1..3 = mlp1_w[l], 4..6 = mlp2_w[l]
__global__ __launch_bounds__(512) void pack_w_kernel(
    const float* __restrict__ w_node, const float* __restrict__ mlp1_w,
    const float* __restrict__ mlp2_w, v8h* __restrict__ Wpk)
{
    const int m = blockIdx.x;
    const float* W = (m == 0) ? w_node
                   : (m <= 3) ? mlp1_w + (m-1)*4096
                              : mlp2_w + (m-4)*4096;
    const int fid = threadIdx.x >> 6;
    const int l   = threadIdx.x & 63;
    const int t = fid >> 1, f = fid & 1;
    const int n  = (l & 15) + 16*t;
    const int kb = f*32 + (l >> 4)*8;
    v8h v;
    #pragma unroll
    for (int j = 0; j < 8; ++j) v[j] = (_Float16)W[(kb + j)*64 + n];
    Wpk[m*512 + fid*64 + l] = v;
}

// ---------------------------------------------------------------------------
// CSR build: histogram of dst
__global__ __launch_bounds__(256) void hist_kernel(
    const int* __restrict__ dst, int* __restrict__ counts)
{
    const int e = blockIdx.x * 256 + threadIdx.x;
    if (e < NE) atomicAdd(&counts[dst[e]], 1);
}

__global__ __launch_bounds__(256) void scan_reduce_kernel(
    const int* __restrict__ counts, int* __restrict__ bsum)
{
    __shared__ int sd[256];
    const int t = threadIdx.x;
    const int idx = blockIdx.x * 256 + t;
    sd[t] = (idx < NN) ? counts[idx] : 0;
    __syncthreads();
    for (int off = 128; off > 0; off >>= 1) {
        if (t < off) sd[t] += sd[t + off];
        __syncthreads();
    }
    if (t == 0) bsum[blockIdx.x] = sd[0];
}

__global__ __launch_bounds__(512) void scan_partials_kernel(
    const int* __restrict__ bsum, int* __restrict__ bscan)
{
    __shared__ int sd[512];
    const int t = threadIdx.x;
    sd[t] = (t < NB_SCAN) ? bsum[t] : 0;
    __syncthreads();
    for (int off = 1; off < 512; off <<= 1) {
        int u = (t >= off) ? sd[t - off] : 0;
        __syncthreads();
        sd[t] += u;
        __syncthreads();
    }
    if (t < NB_SCAN) bscan[t] = (t == 0) ? 0 : sd[t - 1];
}

__global__ __launch_bounds__(256) void scan_final_kernel(
    const int* __restrict__ counts, const int* __restrict__ bscan,
    int* __restrict__ rowptr, int* __restrict__ next)
{
    __shared__ int sd[256];
    const int t = threadIdx.x;
    const int idx = blockIdx.x * 256 + t;
    const int v = (idx < NN) ? counts[idx] : 0;
    sd[t] = v;
    __syncthreads();
    for (int off = 1; off < 256; off <<= 1) {
        int u = (t >= off) ? sd[t - off] : 0;
        __syncthreads();
        sd[t] += u;
        __syncthreads();
    }
    const int excl = sd[t] - v + bscan[blockIdx.x];
    if (idx < NN) { rowptr[idx] = excl; next[idx] = excl; }
    if (idx == NN - 1) rowptr[NN] = excl + v;
}

// scatter: src index + f16-packed edge_attr row into CSR order
__global__ __launch_bounds__(256) void scatter_kernel(
    const int* __restrict__ src, const int* __restrict__ dst,
    const float* __restrict__ edge_attr,
    int* __restrict__ next, int* __restrict__ csr_src, uint4* __restrict__ csr_ea)
{
    const int e = blockIdx.x * 256 + threadIdx.x;
    if (e >= NE) return;
    const float4* q = (const float4*)(edge_attr + (size_t)e * 16);
    float4 a0 = q[0], a1 = q[1], a2 = q[2], a3 = q[3];
    const int pos = atomicAdd(&next[dst[e]], 1);
    csr_src[pos] = src[e];
    uint4 A, B;
    A.x = packh2(a0.x, a0.y); A.y = packh2(a0.z, a0.w);
    A.z = packh2(a1.x, a1.y); A.w = packh2(a1.z, a1.w);
    B.x = packh2(a2.x, a2.y); B.y = packh2(a2.z, a2.w);
    B.z = packh2(a3.x, a3.y); B.w = packh2(a3.z, a3.w);
    csr_ea[(size_t)pos*2 + 0] = A;
    csr_ea[(size_t)pos*2 + 1] = B;
}

// ---------------------------------------------------------------------------
// aggregation: one wave per node, lanes = 64 feature columns.
// Software-pipelined (ping-pong groups of 4 edges): group g+1's src/ea loads
// issue before group g's compute; g+1's h-gathers issue after (src landed
// under the compute); raw f16 gathers convert at the consuming use.
// Self-term from fp32 h (exact). Output f16 (mlp1's MFMA A-operand).
__global__ __launch_bounds__(256) void agg_kernel(
    const int* __restrict__ rowptr, const int* __restrict__ csr_src,
    const uint4* __restrict__ csr_ea,
    const unsigned* __restrict__ Wc16, const float* __restrict__ bc,
    const float* __restrict__ h, const _Float16* __restrict__ h16,
    _Float16* __restrict__ out16)
{
    const int tid = threadIdx.x;
    const int lane = tid & 63;
    const int n = blockIdx.x * 4 + (tid >> 6);
    if (n >= NN) return;

    unsigned wq[8];
    #pragma unroll
    for (int j = 0; j < 8; ++j) wq[j] = Wc16[j*64 + lane];
    const float mb = bc[lane];

    const int start = rowptr[n], end = rowptr[n + 1];
    float acc = h[(size_t)n * 64 + lane];            // fused "+ h" (GINE eps=0)
    const int deg = end - start;
    if (deg <= 0) { out16[(size_t)n*64 + lane] = (_Float16)acc; return; }
    const int ngrp = (deg + 3) >> 2;
    const int last = end - 1;

    struct Grp { int s[4]; uint4 ea[8]; _Float16 hv[4]; };
    Grp G0, G1;

    auto load_se = [&](int p, Grp& G) {
        #pragma unroll
        for (int j = 0; j < 4; ++j) {
            int pj = p + j; pj = pj > last ? last : pj;
            G.s[j] = csr_src[pj];
            G.ea[j*2+0] = csr_ea[(size_t)pj*2 + 0];
            G.ea[j*2+1] = csr_ea[(size_t)pj*2 + 1];
        }
    };
    auto gath = [&](Grp& G) {
        #pragma unroll
        for (int j = 0; j < 4; ++j) G.hv[j] = h16[(size_t)G.s[j]*64 + lane];
    };
    auto comp = [&](int p, const Grp& G) {
        #pragma unroll
        for (int j = 0; j < 4; ++j) {
            float m = mb;
            m = dot2f(G.ea[j*2+0].x, wq[0], m); m = dot2f(G.ea[j*2+0].y, wq[1], m);
            m = dot2f(G.ea[j*2+0].z, wq[2], m); m = dot2f(G.ea[j*2+0].w, wq[3], m);
            m = dot2f(G.ea[j*2+1].x, wq[4], m); m = dot2f(G.ea[j*2+1].y, wq[5], m);
            m = dot2f(G.ea[j*2+1].z, wq[6], m); m = dot2f(G.ea[j*2+1].w, wq[7], m);
            if (p + j < end) acc += fmaxf(m + (float)G.hv[j], 0.f);
        }
    };

    load_se(start, G0);
    gath(G0);
    int p = start, g = 0;
    while (true) {
        if (g + 1 < ngrp) load_se(p + 4, G1);
        comp(p, G0);
        if (g + 1 < ngrp) gath(G1);
        ++g; p += 4;
        if (g >= ngrp) break;
        if (g + 1 < ngrp) load_se(p + 4, G0);
        comp(p, G1);
        if (g + 1 < ngrp) gath(G0);
        ++g; p += 4;
        if (g >= ngrp) break;
    }
    out16[(size_t)n*64 + lane] = (_Float16)acc;
}

// ---------------------------------------------------------------------------
// MFMA node GEMM: [NN,64] @ [64,64] + bias.
// One wave = 16 rows x 64 cols (4 C-tiles, K=64 -> 2 mfma/tile).
// IN_HALF: A from f16; else fp32 (+ relu(a*scale+shift) if TRANS).
template<bool IN_HALF, bool TRANS, bool OUT_RELU, bool OUT_ACCUM, bool OUT_HALF>
__global__ __launch_bounds__(256) void mfma_gemm_kernel(
    const float* __restrict__ in0, const _Float16* __restrict__ in16,
    const v8h* __restrict__ Wpk, const float* __restrict__ bias,
    const float* __restrict__ scale, const float* __restrict__ shift,
    float* __restrict__ out, _Float16* __restrict__ out16,
    float* __restrict__ bn_sum, float* __restrict__ bn_sumsq)
{
    __shared__ float sS[1024];
    __shared__ float sQ[1024];
    const int tid = threadIdx.x;
    const int wv = tid >> 6, l = tid & 63;
    const int li = l & 15, quad = l >> 4;
    const int rb = (blockIdx.x * 4 + wv) * 16;   // row-block base
    const bool active = (rb < NN);               // NN % 16 == 0

    v8h Bf[8];
    #pragma unroll
    for (int i = 0; i < 8; ++i) Bf[i] = Wpk[i*64 + l];

    v4f acc[4] = {v4f{0,0,0,0}, v4f{0,0,0,0}, v4f{0,0,0,0}, v4f{0,0,0,0}};

    if (active) {
        v8h Af[2];
        if constexpr (IN_HALF) {
            const _Float16* arow = in16 + (size_t)(rb + li)*64 + quad*8;
            Af[0] = *(const v8h*)(arow);
            Af[1] = *(const v8h*)(arow + 32);
        } else {
            const float* arow = in0 + (size_t)(rb + li)*64 + quad*8;
            #pragma unroll
            for (int f = 0; f < 2; ++f) {
                float4 x0 = *(const float4*)(arow + f*32);
                float4 x1 = *(const float4*)(arow + f*32 + 4);
                if constexpr (TRANS) {
                    const int kb = f*32 + quad*8;
                    float4 s0 = *(const float4*)(scale + kb);
                    float4 s1 = *(const float4*)(scale + kb + 4);
                    float4 t0 = *(const float4*)(shift + kb);
                    float4 t1 = *(const float4*)(shift + kb + 4);
                    x0.x = fmaxf(fmaf(x0.x, s0.x, t0.x), 0.f);
                    x0.y = fmaxf(fmaf(x0.y, s0.y, t0.y), 0.f);
                    x0.z = fmaxf(fmaf(x0.z, s0.z, t0.z), 0.f);
                    x0.w = fmaxf(fmaf(x0.w, s0.w, t0.w), 0.f);
                    x1.x = fmaxf(fmaf(x1.x, s1.x, t1.x), 0.f);
                    x1.y = fmaxf(fmaf(x1.y, s1.y, t1.y), 0.f);
                    x1.z = fmaxf(fmaf(x1.z, s1.z, t1.z), 0.f);
                    x1.w = fmaxf(fmaf(x1.w, s1.w, t1.w), 0.f);
                }
                v8h a;
                a[0] = (_Float16)x0.x; a[1] = (_Float16)x0.y;
                a[2] = (_Float16)x0.z; a[3] = (_Float16)x0.w;
                a[4] = (_Float16)x1.x; a[5] = (_Float16)x1.y;
                a[6] = (_Float16)x1.z; a[7] = (_Float16)x1.w;
                Af[f] = a;
            }
        }
        #pragma unroll
        for (int t = 0; t < 4; ++t) {
            acc[t] = __builtin_amdgcn_mfma_f32_16x16x32_f16(Af[0], Bf[t*2+0], acc[t], 0, 0, 0);
            acc[t] = __builtin_amdgcn_mfma_f32_16x16x32_f16(Af[1], Bf[t*2+1], acc[t], 0, 0, 0);
        }
    }

    float ps[4] = {0.f, 0.f, 0.f, 0.f}, pq[4] = {0.f, 0.f, 0.f, 0.f};
    if (active) {
        #pragma unroll
        for (int t = 0; t < 4; ++t) {
            const int col = li + 16*t;
            const float bcol = bias[col];
            #pragma unroll
            for (int r = 0; r < 4; ++r) {
                const int row = rb + quad*4 + r;
                float v = acc[t][r] + bcol;
                if constexpr (OUT_ACCUM) { ps[t] += v; pq[t] += v*v; }
                if constexpr (OUT_RELU) v = fmaxf(v, 0.f);
                out[(size_t)row*64 + col] = v;
                if constexpr (OUT_HALF) out16[(size_t)row*64 + col] = (_Float16)v;
            }
        }
    }

    if constexpr (OUT_ACCUM) {
        #pragma unroll
        for (int t = 0; t < 4; ++t) {
            sS[wv*256 + l*4 + t] = ps[t];
            sQ[wv*256 + l*4 + t] = pq[t];
        }
        __syncthreads();
        if (tid < 64) {
            const int t = tid >> 4, li2 = tid & 15;
            float s = 0.f, q = 0.f;
            #pragma unroll
            for (int w = 0; w < 4; ++w)
                #pragma unroll
                for (int qd = 0; qd < 4; ++qd) {
                    const int idx = w*256 + (qd*16 + li2)*4 + t;
                    s += sS[idx]; q += sQ[idx];
                }
            atomicAdd(bn_sum + tid, s);
            atomicAdd(bn_sumsq + tid, q);
        }
    }
}

// ---------------------------------------------------------------------------
// small vector GEMM for the 512-row head
template<int IN_MODE, bool OUT_RELU, bool OUT_ACCUM>
__global__ __launch_bounds__(256) void gemm64_kernel(
    const float* __restrict__ in0,
    const float* __restrict__ W, const float* __restrict__ bias,
    const float* __restrict__ scale, const float* __restrict__ shift,
    float* __restrict__ out, int nrows,
    float* __restrict__ bn_sum, float* __restrict__ bn_sumsq)
{
    __shared__ __align__(16) float sIn[64*64];
    __shared__ float sRedS[512];
    __shared__ float sRedQ[512];
    const int tid = threadIdx.x;
    const int c  = tid & 31;
    const int rg = tid >> 5;
    const int r0 = blockIdx.x * 64;

    float w0[64], w1[64];
    #pragma unroll
    for (int k = 0; k < 64; ++k) { w0[k] = W[k*64 + c]; w1[k] = W[k*64 + c + 32]; }
    const float b0 = bias[c], b1 = bias[c + 32];

    for (int i = tid; i < 1024; i += 256) {
        const int r  = i >> 4;
        const int c4 = (i & 15) * 4;
        const int gr = r0 + r;
        float4 v = make_float4(0.f, 0.f, 0.f, 0.f);
        if (gr < nrows) {
            v = *(const float4*)(in0 + (size_t)gr*64 + c4);
            if constexpr (IN_MODE == 2) {
                float4 s4 = *(const float4*)(scale + c4);
                float4 h4 = *(const float4*)(shift + c4);
                v.x = fmaxf(fmaf(v.x, s4.x, h4.x), 0.f);
                v.y = fmaxf(fmaf(v.y, s4.y, h4.y), 0.f);
                v.z = fmaxf(fmaf(v.z, s4.z, h4.z), 0.f);
                v.w = fmaxf(fmaf(v.w, s4.w, h4.w), 0.f);
            }
        }
        *(float4*)(sIn + r*64 + c4) = v;
    }
    __syncthreads();

    float ps0 = 0.f, psq0 = 0.f, ps1 = 0.f, psq1 = 0.f;
    #pragma unroll
    for (int i = 0; i < 8; ++i) {
        const int r = rg + 8*i;
        float a0 = b0, a1 = b1;
        #pragma unroll
        for (int k = 0; k < 64; k += 4) {
            float4 a = *(const float4*)(sIn + r*64 + k);
            a0 = fmaf(a.x, w0[k+0], a0); a1 = fmaf(a.x, w1[k+0], a1);
            a0 = fmaf(a.y, w0[k+1], a0); a1 = fmaf(a.y, w1[k+1], a1);
            a0 = fmaf(a.z, w0[k+2], a0); a1 = fmaf(a.z, w1[k+2], a1);
            a0 = fmaf(a.w, w0[k+3], a0); a1 = fmaf(a.w, w1[k+3], a1);
        }
        const int gr = r0 + r;
        if (gr < nrows) {
            if constexpr (OUT_ACCUM) {
                ps0 += a0; psq0 += a0*a0;
                ps1 += a1; psq1 += a1*a1;
            }
            out[(size_t)gr*64 + c]      = OUT_RELU ? fmaxf(a0, 0.f) : a0;
            out[(size_t)gr*64 + c + 32] = OUT_RELU ? fmaxf(a1, 0.f) : a1;
        }
    }

    if constexpr (OUT_ACCUM) {
        sRedS[rg*64 + c]      = ps0;
        sRedS[rg*64 + c + 32] = ps1;
        sRedQ[rg*64 + c]      = psq0;
        sRedQ[rg*64 + c + 32] = psq1;
        __syncthreads();
        if (tid < 64) {
            float s = 0.f, q = 0.f;
            #pragma unroll
            for (int g = 0; g < 8; ++g) { s += sRedS[g*64 + tid]; q += sRedQ[g*64 + tid]; }
            atomicAdd(bn_sum + tid, s);
            atomicAdd(bn_sumsq + tid, q);
        }
    }
}

// ---------------------------------------------------------------------------
__global__ __launch_bounds__(64) void bn_finalize_kernel(
    const float* __restrict__ sum, const float* __restrict__ sumsq,
    const float* __restrict__ gamma, const float* __restrict__ beta,
    float inv_count, float* __restrict__ scale, float* __restrict__ shift)
{
    const int t = threadIdx.x;
    float mu  = sum[t] * inv_count;
    float var = fmaxf(sumsq[t] * inv_count - mu*mu, 0.f);
    float x = var + 1e-5f;
    float r = rsqrtf(x);
    r = r * (1.5f - 0.5f * x * r * r);
    float sc = gamma[t] * r;
    scale[t] = sc;
    shift[t] = beta[t] - mu * sc;
}

// ---------------------------------------------------------------------------
__global__ __launch_bounds__(256) void pool_kernel(
    const float* __restrict__ h, const int* __restrict__ batch,
    float* __restrict__ pooled)
{
    __shared__ float sRed[256];
    const int g = blockIdx.x;
    const int tid = threadIdx.x;
    const int lane = tid & 63, wave = tid >> 6;
    int lo = 0, hi = NN;
    while (lo < hi) { int m = (lo + hi) >> 1; if (batch[m] < g) lo = m + 1; else hi = m; }
    const int start = lo;
    hi = NN;
    while (lo < hi) { int m = (lo + hi) >> 1; if (batch[m] < g + 1) lo = m + 1; else hi = m; }
    const int end = lo;
    float acc = 0.f;
    for (int n = start + wave; n < end; n += 4) acc += h[(size_t)n*64 + lane];
    sRed[tid] = acc;
    __syncthreads();
    if (tid < 64)
        pooled[g*64 + tid] = sRed[tid] + sRed[64+tid] + sRed[128+tid] + sRed[192+tid];
}

// ---------------------------------------------------------------------------
__global__ __launch_bounds__(256) void head_final_kernel(
    const float* __restrict__ hb, const float* __restrict__ scale,
    const float* __restrict__ shift, const float* __restrict__ fo3_w,
    const float* __restrict__ fo3_b, float* __restrict__ out)
{
    const int idx = blockIdx.x * 256 + threadIdx.x;
    if (idx >= NG * NC) return;
    const int g = idx / NC, c = idx % NC;
    float acc = fo3_b[c];
    for (int k = 0; k < 64; ++k) {
        float v = fmaf(hb[g*64 + k], scale[k], shift[k]);
        acc = fmaf(v, fo3_w[k*NC + c], acc);
    }
    out[idx] = acc;
}

// ---------------------------------------------------------------------------
extern "C" void kernel_launch(void* const* d_in, const int* in_sizes, int n_in,
                              void* d_out, int out_size, void* d_ws, size_t ws_size,
                              hipStream_t stream) {
    const float* x         = (const float*)d_in[0];
    const int*   edge_index= (const int*)  d_in[1];
    const int*   batch     = (const int*)  d_in[2];
    const float* edge_attr = (const float*)d_in[3];
    const float* w_node    = (const float*)d_in[4];
    const float* b_node    = (const float*)d_in[5];
    const float* w_edge    = (const float*)d_in[6];
    const float* b_edge    = (const float*)d_in[7];
    const float* lin_w     = (const float*)d_in[8];
    const float* lin_b     = (const float*)d_in[9];
    const float* mlp1_w    = (const float*)d_in[10];
    const float* mlp1_b    = (const float*)d_in[11];
    const float* bn1_g     = (const float*)d_in[12];
    const float* bn1_b     = (const float*)d_in[13];
    const float* mlp2_w    = (const float*)d_in[14];
    const float* mlp2_b    = (const float*)d_in[15];
    const float* fo1_w     = (const float*)d_in[16];
    const float* fo1_b     = (const float*)d_in[17];
    const float* fo_bn1_g  = (const float*)d_in[18];
    const float* fo_bn1_b  = (const float*)d_in[19];
    const float* fo2_w     = (const float*)d_in[20];
    const float* fo2_b     = (const float*)d_in[21];
    const float* fo_bn2_g  = (const float*)d_in[22];
    const float* fo_bn2_b  = (const float*)d_in[23];
    const float* fo3_w     = (const float*)d_in[24];
    const float* fo3_b     = (const float*)d_in[25];
    float* out = (float*)d_out;

    char* ws = (char*)d_ws;
    float* h    = (float*)(ws);                    // 25.6 MB
    float* t    = (float*)(ws + 25600000);         // 25.6 MB (CSR-build ints alias)
    int* counts = (int*)t;                         // NN ints (dead before t written)
    int* next   = (int*)t + NN;                    // NN ints (dead after scatter)
    int*   csr_src = (int*)(ws + 51200000);        // 4.8 MB
    uint4* csr_ea  = (uint4*)(ws + 56000000);      // 38.4 MB
    int* rowptr = (int*)(ws + 94400000);           // NN+1 ints
    _Float16* h16   = (_Float16*)(ws + 94900000);  // 12.8 MB
    _Float16* agg16 = (_Float16*)(ws + 107700000); // 12.8 MB
    float* sm   = (float*)(ws + 120500000);
    unsigned* Wc16 = (unsigned*)sm;  // 3*512 uints (edge weights f16)
    float* bc       = sm + 1536;     // 192
    float* scale    = sm + 1728;     // 64
    float* shift    = sm + 1792;     // 64
    float* bn_sum   = sm + 1856;     // 64
    float* bn_sumsq = sm + 1920;     // 64
    float* pooled   = sm + 1984;     // 32768
    float* ha       = sm + 34752;    // 32768
    float* hb       = sm + 67520;    // 32768
    int* bsum       = (int*)(sm + 100288);   // NB_SCAN ints
    int* bscan      = bsum + 512;
    v8h* Wpk        = (v8h*)(sm + 101376);   // 7*512*16 B (16B-aligned)

    const int* src = edge_index;
    const int* dst = edge_index + NE;

    const int mfma_blocks  = (NN/16 + 3) / 4;    // 1563
    const int edge_blocks  = (NE + 255) / 256;   // 4688
    const int agg_blocks   = (NN + 3) / 4;       // 25000

    prep_kernel<<<NL, 1024, 0, stream>>>(w_edge, b_edge, lin_w, lin_b, Wc16, bc);
    pack_w_kernel<<<7, 512, 0, stream>>>(w_node, mlp1_w, mlp2_w, Wpk);

    // h = x @ w_node + b_node  (fp32 + f16 mirror)
    mfma_gemm_kernel<false, false, false, false, true><<<mfma_blocks, 256, 0, stream>>>(
        x, nullptr, Wpk, b_node, nullptr, nullptr, h, h16, nullptr, nullptr);

    // CSR build (per launch; edge_index is an input)
    hipMemsetAsync(counts, 0, NN * sizeof(int), stream);
    hist_kernel<<<edge_blocks, 256, 0, stream>>>(dst, counts);
    scan_reduce_kernel<<<NB_SCAN, 256, 0, stream>>>(counts, bsum);
    scan_partials_kernel<<<1, 512, 0, stream>>>(bsum, bscan);
    scan_final_kernel<<<NB_SCAN, 256, 0, stream>>>(counts, bscan, rowptr, next);
    scatter_kernel<<<edge_blocks, 256, 0, stream>>>(
        src, dst, edge_attr, next, csr_src, csr_ea);

    for (int l = 0; l < NL; ++l) {
        agg_kernel<<<agg_blocks, 256, 0, stream>>>(
            rowptr, csr_src, csr_ea, Wc16 + l*512, bc + l*64, h, h16, agg16);
        hipMemsetAsync(bn_sum, 0, 128 * sizeof(float), stream);
        // t = agg16 @ mlp1_w + b  (fp32 out) + BN stats
        mfma_gemm_kernel<true, false, false, true, false><<<mfma_blocks, 256, 0, stream>>>(
            nullptr, agg16, Wpk + (1+l)*512, mlp1_b + l*64, nullptr, nullptr,
            t, nullptr, bn_sum, bn_sumsq);
        bn_finalize_kernel<<<1, 64, 0, stream>>>(
            bn_sum, bn_sumsq, bn1_g + l*64, bn1_b + l*64, 1.0f / NN, scale, shift);
        // h = relu( relu(bn(t)) @ mlp2_w + b )  (fp32 + f16 mirror)
        mfma_gemm_kernel<false, true, true, false, true><<<mfma_blocks, 256, 0, stream>>>(
            t, nullptr, Wpk + (4+l)*512, mlp2_b + l*64, scale, shift,
            h, h16, nullptr, nullptr);
    }

    pool_kernel<<<NG, 256, 0, stream>>>(h, batch, pooled);

    hipMemsetAsync(bn_sum, 0, 128 * sizeof(float), stream);
    gemm64_kernel<0, false, true><<<NG/64, 256, 0, stream>>>(
        pooled, fo1_w, fo1_b, nullptr, nullptr, ha, NG, bn_sum, bn_sumsq);
    bn_finalize_kernel<<<1, 64, 0, stream>>>(
        bn_sum, bn_sumsq, fo_bn1_g, fo_bn1_b, 1.0f / NG, scale, shift);
    hipMemsetAsync(bn_sum, 0, 128 * sizeof(float), stream);
    gemm64_kernel<2, false, true><<<NG/64, 256, 0, stream>>>(
        ha, fo2_w, fo2_b, scale, shift, hb, NG, bn_sum, bn_sumsq);
    bn_finalize_kernel<<<1, 64, 0, stream>>>(
        bn_sum, bn_sumsq, fo_bn2_g, fo_bn2_b, 1.0f / NG, scale, shift);
    head_final_kernel<<<(NG*NC + 255)/256, 256, 0, stream>>>(
        hb, scale, shift, fo3_w, fo3_b, out);
}

// Round 10
// 872.427 us; speedup vs baseline: 1.0907x; 1.0907x over previous
//
#include <hip/hip_runtime.h>

#define NN 100000
#define NE 1200000
#define DD 64
#define EDIM 16
#define NL 3
#define NG 512
#define NC 10
#define NB_SCAN ((NN + 255) / 256)   // 391

typedef _Float16 f16x2 __attribute__((ext_vector_type(2)));
typedef _Float16 v8h   __attribute__((ext_vector_type(8)));
typedef float    v4f   __attribute__((ext_vector_type(4)));

__device__ __forceinline__ unsigned packh2(float a, float b) {
    f16x2 v; v[0] = (_Float16)a; v[1] = (_Float16)b;
    unsigned u; __builtin_memcpy(&u, &v, 4); return u;
}
__device__ __forceinline__ float dot2f(unsigned a, unsigned b, float c) {
    f16x2 av, bv;
    __builtin_memcpy(&av, &a, 4); __builtin_memcpy(&bv, &b, 4);
#if __has_builtin(__builtin_amdgcn_fdot2)
    return __builtin_amdgcn_fdot2(av, bv, c, false);
#else
    return c + (float)av[0]*(float)bv[0] + (float)av[1]*(float)bv[1];
#endif
}

// ---------------------------------------------------------------------------
// prep: Wc[l] = w_edge @ lin_w[l] (16x64) packed to f16 pairs per column;
//       bc[l] = b_edge @ lin_w[l] + lin_b[l]  (fp32)
__global__ __launch_bounds__(1024) void prep_kernel(
    const float* __restrict__ w_edge, const float* __restrict__ b_edge,
    const float* __restrict__ lin_w, const float* __restrict__ lin_b,
    unsigned* __restrict__ Wc16, float* __restrict__ bc)
{
    __shared__ float sWc[1024];
    const int l = blockIdx.x;
    const int tid = threadIdx.x;
    const float* Lw = lin_w + l * 4096;
    const int k = tid >> 6, col = tid & 63;
    float acc = 0.f;
    for (int j = 0; j < 64; ++j) acc = fmaf(w_edge[k*64 + j], Lw[j*64 + col], acc);
    sWc[k*64 + col] = acc;
    if (tid < 64) {
        float a = lin_b[l*64 + tid];
        for (int j = 0; j < 64; ++j) a = fmaf(b_edge[j], Lw[j*64 + tid], a);
        bc[l*64 + tid] = a;
    }
    __syncthreads();
    if (tid < 512) {
        const int j = tid >> 6, c = tid & 63;     // j = pair index (dims 2j,2j+1)
        Wc16[l*512 + j*64 + c] = packh2(sWc[(2*j)*64 + c], sWc[(2*j+1)*64 + c]);
    }
}

// ---------------------------------------------------------------------------
// pack node-GEMM weights [64x64] fp32 -> f16 MFMA B-fragment order.
// m: 0 = w_node, 1..3 = mlp1_w[l], 4..6 = mlp2_w[l]
__global__ __launch_bounds__(512) void pack_w_kernel(
    const float* __restrict__ w_node, const float* __restrict__ mlp1_w,
    const float* __restrict__ mlp2_w, v8h* __restrict__ Wpk)
{
    const int m = blockIdx.x;
    const float* W = (m == 0) ? w_node
                   : (m <= 3) ? mlp1_w + (m-1)*4096
                              : mlp2_w + (m-4)*4096;
    const int fid = threadIdx.x >> 6;
    const int l   = threadIdx.x & 63;
    const int t = fid >> 1, f = fid & 1;
    const int n  = (l & 15) + 16*t;
    const int kb = f*32 + (l >> 4)*8;
    v8h v;
    #pragma unroll
    for (int j = 0; j < 8; ++j) v[j] = (_Float16)W[(kb + j)*64 + n];
    Wpk[m*512 + fid*64 + l] = v;
}

// ---------------------------------------------------------------------------
// CSR build: histogram of dst
__global__ __launch_bounds__(256) void hist_kernel(
    const int* __restrict__ dst, int* __restrict__ counts)
{
    const int e = blockIdx.x * 256 + threadIdx.x;
    if (e < NE) atomicAdd(&counts[dst[e]], 1);
}

__global__ __launch_bounds__(256) void scan_reduce_kernel(
    const int* __restrict__ counts, int* __restrict__ bsum)
{
    __shared__ int sd[256];
    const int t = threadIdx.x;
    const int idx = blockIdx.x * 256 + t;
    sd[t] = (idx < NN) ? counts[idx] : 0;
    __syncthreads();
    for (int off = 128; off > 0; off >>= 1) {
        if (t < off) sd[t] += sd[t + off];
        __syncthreads();
    }
    if (t == 0) bsum[blockIdx.x] = sd[0];
}

__global__ __launch_bounds__(512) void scan_partials_kernel(
    const int* __restrict__ bsum, int* __restrict__ bscan)
{
    __shared__ int sd[512];
    const int t = threadIdx.x;
    sd[t] = (t < NB_SCAN) ? bsum[t] : 0;
    __syncthreads();
    for (int off = 1; off < 512; off <<= 1) {
        int u = (t >= off) ? sd[t - off] : 0;
        __syncthreads();
        sd[t] += u;
        __syncthreads();
    }
    if (t < NB_SCAN) bscan[t] = (t == 0) ? 0 : sd[t - 1];
}

__global__ __launch_bounds__(256) void scan_final_kernel(
    const int* __restrict__ counts, const int* __restrict__ bscan,
    int* __restrict__ rowptr, int* __restrict__ next)
{
    __shared__ int sd[256];
    const int t = threadIdx.x;
    const int idx = blockIdx.x * 256 + t;
    const int v = (idx < NN) ? counts[idx] : 0;
    sd[t] = v;
    __syncthreads();
    for (int off = 1; off < 256; off <<= 1) {
        int u = (t >= off) ? sd[t - off] : 0;
        __syncthreads();
        sd[t] += u;
        __syncthreads();
    }
    const int excl = sd[t] - v + bscan[blockIdx.x];
    if (idx < NN) { rowptr[idx] = excl; next[idx] = excl; }
    if (idx == NN - 1) rowptr[NN] = excl + v;
}

// scatter: src index + f16-packed edge_attr row into CSR order
__global__ __launch_bounds__(256) void scatter_kernel(
    const int* __restrict__ src, const int* __restrict__ dst,
    const float* __restrict__ edge_attr,
    int* __restrict__ next, int* __restrict__ csr_src, uint4* __restrict__ csr_ea)
{
    const int e = blockIdx.x * 256 + threadIdx.x;
    if (e >= NE) return;
    const float4* q = (const float4*)(edge_attr + (size_t)e * 16);
    float4 a0 = q[0], a1 = q[1], a2 = q[2], a3 = q[3];
    const int pos = atomicAdd(&next[dst[e]], 1);
    csr_src[pos] = src[e];
    uint4 A, B;
    A.x = packh2(a0.x, a0.y); A.y = packh2(a0.z, a0.w);
    A.z = packh2(a1.x, a1.y); A.w = packh2(a1.z, a1.w);
    B.x = packh2(a2.x, a2.y); B.y = packh2(a2.z, a2.w);
    B.z = packh2(a3.x, a3.y); B.w = packh2(a3.z, a3.w);
    csr_ea[(size_t)pos*2 + 0] = A;
    csr_ea[(size_t)pos*2 + 1] = B;
}

// ---------------------------------------------------------------------------
// aggregation: one wave per node, lanes = 64 feature columns. Simple x4-
// unrolled loop (occupancy-driven latency hiding beats SW pipelining here:
// R9 showed pipelined version costs 20 VGPR -> 36% occupancy -> +20% time).
// Self-term and gathers from h16.
__global__ __launch_bounds__(256) void agg_kernel(
    const int* __restrict__ rowptr, const int* __restrict__ csr_src,
    const uint4* __restrict__ csr_ea,
    const unsigned* __restrict__ Wc16, const float* __restrict__ bc,
    const _Float16* __restrict__ h16, _Float16* __restrict__ out16)
{
    const int tid = threadIdx.x;
    const int lane = tid & 63;
    const int n = blockIdx.x * 4 + (tid >> 6);
    if (n >= NN) return;

    unsigned wq[8];
    #pragma unroll
    for (int j = 0; j < 8; ++j) wq[j] = Wc16[j*64 + lane];
    const float mb = bc[lane];

    const int start = rowptr[n], end = rowptr[n + 1];
    float acc = (float)h16[(size_t)n * 64 + lane];   // fused "+ h" (GINE eps=0)

    auto msg = [&](uint4 A, uint4 B, float hv) -> float {
        float m = mb;
        m = dot2f(A.x, wq[0], m); m = dot2f(A.y, wq[1], m);
        m = dot2f(A.z, wq[2], m); m = dot2f(A.w, wq[3], m);
        m = dot2f(B.x, wq[4], m); m = dot2f(B.y, wq[5], m);
        m = dot2f(B.z, wq[6], m); m = dot2f(B.w, wq[7], m);
        return fmaxf(m + hv, 0.f);
    };

    int p = start;
    for (; p + 4 <= end; p += 4) {
        const int s0 = csr_src[p+0], s1 = csr_src[p+1];
        const int s2 = csr_src[p+2], s3 = csr_src[p+3];
        uint4 A0 = csr_ea[(size_t)(p+0)*2], B0 = csr_ea[(size_t)(p+0)*2 + 1];
        uint4 A1 = csr_ea[(size_t)(p+1)*2], B1 = csr_ea[(size_t)(p+1)*2 + 1];
        uint4 A2 = csr_ea[(size_t)(p+2)*2], B2 = csr_ea[(size_t)(p+2)*2 + 1];
        uint4 A3 = csr_ea[(size_t)(p+3)*2], B3 = csr_ea[(size_t)(p+3)*2 + 1];
        float hv0 = (float)h16[(size_t)s0 * 64 + lane];
        float hv1 = (float)h16[(size_t)s1 * 64 + lane];
        float hv2 = (float)h16[(size_t)s2 * 64 + lane];
        float hv3 = (float)h16[(size_t)s3 * 64 + lane];
        acc += msg(A0, B0, hv0);
        acc += msg(A1, B1, hv1);
        acc += msg(A2, B2, hv2);
        acc += msg(A3, B3, hv3);
    }
    for (; p < end; ++p) {
        const int s0 = csr_src[p];
        uint4 A = csr_ea[(size_t)p*2], B = csr_ea[(size_t)p*2 + 1];
        float hv = (float)h16[(size_t)s0 * 64 + lane];
        acc += msg(A, B, hv);
    }
    out16[(size_t)n*64 + lane] = (_Float16)acc;
}

// ---------------------------------------------------------------------------
// MFMA node GEMM: [NN,64] @ [64,64] + bias.
// One wave = 16 rows x 64 cols (4 C-tiles, K=64 -> 2 mfma/tile).
// IN_HALF: A from f16; else fp32 (+ relu(a*scale+shift) if TRANS).
// OUT_F32 / OUT_HALF select which outputs are written.
template<bool IN_HALF, bool TRANS, bool OUT_RELU, bool OUT_ACCUM, bool OUT_F32, bool OUT_HALF>
__global__ __launch_bounds__(256) void mfma_gemm_kernel(
    const float* __restrict__ in0, const _Float16* __restrict__ in16,
    const v8h* __restrict__ Wpk, const float* __restrict__ bias,
    const float* __restrict__ scale, const float* __restrict__ shift,
    float* __restrict__ out, _Float16* __restrict__ out16,
    float* __restrict__ bn_sum, float* __restrict__ bn_sumsq)
{
    __shared__ float sS[1024];
    __shared__ float sQ[1024];
    const int tid = threadIdx.x;
    const int wv = tid >> 6, l = tid & 63;
    const int li = l & 15, quad = l >> 4;
    const int rb = (blockIdx.x * 4 + wv) * 16;   // row-block base
    const bool active = (rb < NN);               // NN % 16 == 0

    v8h Bf[8];
    #pragma unroll
    for (int i = 0; i < 8; ++i) Bf[i] = Wpk[i*64 + l];

    v4f acc[4] = {v4f{0,0,0,0}, v4f{0,0,0,0}, v4f{0,0,0,0}, v4f{0,0,0,0}};

    if (active) {
        v8h Af[2];
        if constexpr (IN_HALF) {
            const _Float16* arow = in16 + (size_t)(rb + li)*64 + quad*8;
            Af[0] = *(const v8h*)(arow);
            Af[1] = *(const v8h*)(arow + 32);
        } else {
            const float* arow = in0 + (size_t)(rb + li)*64 + quad*8;
            #pragma unroll
            for (int f = 0; f < 2; ++f) {
                float4 x0 = *(const float4*)(arow + f*32);
                float4 x1 = *(const float4*)(arow + f*32 + 4);
                if constexpr (TRANS) {
                    const int kb = f*32 + quad*8;
                    float4 s0 = *(const float4*)(scale + kb);
                    float4 s1 = *(const float4*)(scale + kb + 4);
                    float4 t0 = *(const float4*)(shift + kb);
                    float4 t1 = *(const float4*)(shift + kb + 4);
                    x0.x = fmaxf(fmaf(x0.x, s0.x, t0.x), 0.f);
                    x0.y = fmaxf(fmaf(x0.y, s0.y, t0.y), 0.f);
                    x0.z = fmaxf(fmaf(x0.z, s0.z, t0.z), 0.f);
                    x0.w = fmaxf(fmaf(x0.w, s0.w, t0.w), 0.f);
                    x1.x = fmaxf(fmaf(x1.x, s1.x, t1.x), 0.f);
                    x1.y = fmaxf(fmaf(x1.y, s1.y, t1.y), 0.f);
                    x1.z = fmaxf(fmaf(x1.z, s1.z, t1.z), 0.f);
                    x1.w = fmaxf(fmaf(x1.w, s1.w, t1.w), 0.f);
                }
                v8h a;
                a[0] = (_Float16)x0.x; a[1] = (_Float16)x0.y;
                a[2] = (_Float16)x0.z; a[3] = (_Float16)x0.w;
                a[4] = (_Float16)x1.x; a[5] = (_Float16)x1.y;
                a[6] = (_Float16)x1.z; a[7] = (_Float16)x1.w;
                Af[f] = a;
            }
        }
        #pragma unroll
        for (int t = 0; t < 4; ++t) {
            acc[t] = __builtin_amdgcn_mfma_f32_16x16x32_f16(Af[0], Bf[t*2+0], acc[t], 0, 0, 0);
            acc[t] = __builtin_amdgcn_mfma_f32_16x16x32_f16(Af[1], Bf[t*2+1], acc[t], 0, 0, 0);
        }
    }

    float ps[4] = {0.f, 0.f, 0.f, 0.f}, pq[4] = {0.f, 0.f, 0.f, 0.f};
    if (active) {
        #pragma unroll
        for (int t = 0; t < 4; ++t) {
            const int col = li + 16*t;
            const float bcol = bias[col];
            #pragma unroll
            for (int r = 0; r < 4; ++r) {
                const int row = rb + quad*4 + r;
                float v = acc[t][r] + bcol;
                if constexpr (OUT_ACCUM) { ps[t] += v; pq[t] += v*v; }
                if constexpr (OUT_RELU) v = fmaxf(v, 0.f);
                if constexpr (OUT_F32)  out[(size_t)row*64 + col] = v;
                if constexpr (OUT_HALF) out16[(size_t)row*64 + col] = (_Float16)v;
            }
        }
    }

    if constexpr (OUT_ACCUM) {
        #pragma unroll
        for (int t = 0; t < 4; ++t) {
            sS[wv*256 + l*4 + t] = ps[t];
            sQ[wv*256 + l*4 + t] = pq[t];
        }
        __syncthreads();
        if (tid < 64) {
            const int t = tid >> 4, li2 = tid & 15;
            float s = 0.f, q = 0.f;
            #pragma unroll
            for (int w = 0; w < 4; ++w)
                #pragma unroll
                for (int qd = 0; qd < 4; ++qd) {
                    const int idx = w*256 + (qd*16 + li2)*4 + t;
                    s += sS[idx]; q += sQ[idx];
                }
            atomicAdd(bn_sum + tid, s);
            atomicAdd(bn_sumsq + tid, q);
        }
    }
}

// ---------------------------------------------------------------------------
// small vector GEMM for the 512-row head
template<int IN_MODE, bool OUT_RELU, bool OUT_ACCUM>
__global__ __launch_bounds__(256) void gemm64_kernel(
    const float* __restrict__ in0,
    const float* __restrict__ W, const float* __restrict__ bias,
    const float* __restrict__ scale, const float* __restrict__ shift,
    float* __restrict__ out, int nrows,
    float* __restrict__ bn_sum, float* __restrict__ bn_sumsq)
{
    __shared__ __align__(16) float sIn[64*64];
    __shared__ float sRedS[512];
    __shared__ float sRedQ[512];
    const int tid = threadIdx.x;
    const int c  = tid & 31;
    const int rg = tid >> 5;
    const int r0 = blockIdx.x * 64;

    float w0[64], w1[64];
    #pragma unroll
    for (int k = 0; k < 64; ++k) { w0[k] = W[k*64 + c]; w1[k] = W[k*64 + c + 32]; }
    const float b0 = bias[c], b1 = bias[c + 32];

    for (int i = tid; i < 1024; i += 256) {
        const int r  = i >> 4;
        const int c4 = (i & 15) * 4;
        const int gr = r0 + r;
        float4 v = make_float4(0.f, 0.f, 0.f, 0.f);
        if (gr < nrows) {
            v = *(const float4*)(in0 + (size_t)gr*64 + c4);
            if constexpr (IN_MODE == 2) {
                float4 s4 = *(const float4*)(scale + c4);
                float4 h4 = *(const float4*)(shift + c4);
                v.x = fmaxf(fmaf(v.x, s4.x, h4.x), 0.f);
                v.y = fmaxf(fmaf(v.y, s4.y, h4.y), 0.f);
                v.z = fmaxf(fmaf(v.z, s4.z, h4.z), 0.f);
                v.w = fmaxf(fmaf(v.w, s4.w, h4.w), 0.f);
            }
        }
        *(float4*)(sIn + r*64 + c4) = v;
    }
    __syncthreads();

    float ps0 = 0.f, psq0 = 0.f, ps1 = 0.f, psq1 = 0.f;
    #pragma unroll
    for (int i = 0; i < 8; ++i) {
        const int r = rg + 8*i;
        float a0 = b0, a1 = b1;
        #pragma unroll
        for (int k = 0; k < 64; k += 4) {
            float4 a = *(const float4*)(sIn + r*64 + k);
            a0 = fmaf(a.x, w0[k+0], a0); a1 = fmaf(a.x, w1[k+0], a1);
            a0 = fmaf(a.y, w0[k+1], a0); a1 = fmaf(a.y, w1[k+1], a1);
            a0 = fmaf(a.z, w0[k+2], a0); a1 = fmaf(a.z, w1[k+2], a1);
            a0 = fmaf(a.w, w0[k+3], a0); a1 = fmaf(a.w, w1[k+3], a1);
        }
        const int gr = r0 + r;
        if (gr < nrows) {
            if constexpr (OUT_ACCUM) {
                ps0 += a0; psq0 += a0*a0;
                ps1 += a1; psq1 += a1*a1;
            }
            out[(size_t)gr*64 + c]      = OUT_RELU ? fmaxf(a0, 0.f) : a0;
            out[(size_t)gr*64 + c + 32] = OUT_RELU ? fmaxf(a1, 0.f) : a1;
        }
    }

    if constexpr (OUT_ACCUM) {
        sRedS[rg*64 + c]      = ps0;
        sRedS[rg*64 + c + 32] = ps1;
        sRedQ[rg*64 + c]      = psq0;
        sRedQ[rg*64 + c + 32] = psq1;
        __syncthreads();
        if (tid < 64) {
            float s = 0.f, q = 0.f;
            #pragma unroll
            for (int g = 0; g < 8; ++g) { s += sRedS[g*64 + tid]; q += sRedQ[g*64 + tid]; }
            atomicAdd(bn_sum + tid, s);
            atomicAdd(bn_sumsq + tid, q);
        }
    }
}

// ---------------------------------------------------------------------------
__global__ __launch_bounds__(64) void bn_finalize_kernel(
    const float* __restrict__ sum, const float* __restrict__ sumsq,
    const float* __restrict__ gamma, const float* __restrict__ beta,
    float inv_count, float* __restrict__ scale, float* __restrict__ shift)
{
    const int t = threadIdx.x;
    float mu  = sum[t] * inv_count;
    float var = fmaxf(sumsq[t] * inv_count - mu*mu, 0.f);
    float x = var + 1e-5f;
    float r = rsqrtf(x);
    r = r * (1.5f - 0.5f * x * r * r);
    float sc = gamma[t] * r;
    scale[t] = sc;
    shift[t] = beta[t] - mu * sc;
}

// ---------------------------------------------------------------------------
// global_add_pool from h16: 4 waves per graph
__global__ __launch_bounds__(256) void pool_kernel(
    const _Float16* __restrict__ h16, const int* __restrict__ batch,
    float* __restrict__ pooled)
{
    __shared__ float sRed[256];
    const int g = blockIdx.x;
    const int tid = threadIdx.x;
    const int lane = tid & 63, wave = tid >> 6;
    int lo = 0, hi = NN;
    while (lo < hi) { int m = (lo + hi) >> 1; if (batch[m] < g) lo = m + 1; else hi = m; }
    const int start = lo;
    hi = NN;
    while (lo < hi) { int m = (lo + hi) >> 1; if (batch[m] < g + 1) lo = m + 1; else hi = m; }
    const int end = lo;
    float acc = 0.f;
    for (int n = start + wave; n < end; n += 4) acc += (float)h16[(size_t)n*64 + lane];
    sRed[tid] = acc;
    __syncthreads();
    if (tid < 64)
        pooled[g*64 + tid] = sRed[tid] + sRed[64+tid] + sRed[128+tid] + sRed[192+tid];
}

// ---------------------------------------------------------------------------
__global__ __launch_bounds__(256) void head_final_kernel(
    const float* __restrict__ hb, const float* __restrict__ scale,
    const float* __restrict__ shift, const float* __restrict__ fo3_w,
    const float* __restrict__ fo3_b, float* __restrict__ out)
{
    const int idx = blockIdx.x * 256 + threadIdx.x;
    if (idx >= NG * NC) return;
    const int g = idx / NC, c = idx % NC;
    float acc = fo3_b[c];
    for (int k = 0; k < 64; ++k) {
        float v = fmaf(hb[g*64 + k], scale[k], shift[k]);
        acc = fmaf(v, fo3_w[k*NC + c], acc);
    }
    out[idx] = acc;
}

// ---------------------------------------------------------------------------
extern "C" void kernel_launch(void* const* d_in, const int* in_sizes, int n_in,
                              void* d_out, int out_size, void* d_ws, size_t ws_size,
                              hipStream_t stream) {
    const float* x         = (const float*)d_in[0];
    const int*   edge_index= (const int*)  d_in[1];
    const int*   batch     = (const int*)  d_in[2];
    const float* edge_attr = (const float*)d_in[3];
    const float* w_node    = (const float*)d_in[4];
    const float* b_node    = (const float*)d_in[5];
    const float* w_edge    = (const float*)d_in[6];
    const float* b_edge    = (const float*)d_in[7];
    const float* lin_w     = (const float*)d_in[8];
    const float* lin_b     = (const float*)d_in[9];
    const float* mlp1_w    = (const float*)d_in[10];
    const float* mlp1_b    = (const float*)d_in[11];
    const float* bn1_g     = (const float*)d_in[12];
    const float* bn1_b     = (const float*)d_in[13];
    const float* mlp2_w    = (const float*)d_in[14];
    const float* mlp2_b    = (const float*)d_in[15];
    const float* fo1_w     = (const float*)d_in[16];
    const float* fo1_b     = (const float*)d_in[17];
    const float* fo_bn1_g  = (const float*)d_in[18];
    const float* fo_bn1_b  = (const float*)d_in[19];
    const float* fo2_w     = (const float*)d_in[20];
    const float* fo2_b     = (const float*)d_in[21];
    const float* fo_bn2_g  = (const float*)d_in[22];
    const float* fo_bn2_b  = (const float*)d_in[23];
    const float* fo3_w     = (const float*)d_in[24];
    const float* fo3_b     = (const float*)d_in[25];
    float* out = (float*)d_out;

    char* ws = (char*)d_ws;
    float* t    = (float*)(ws);                    // 25.6 MB (CSR-build ints alias)
    int* counts = (int*)t;                         // NN ints (dead before t written)
    int* next   = (int*)t + NN;                    // NN ints (dead after scatter)
    int*   csr_src = (int*)(ws + 25600000);        // 4.8 MB
    uint4* csr_ea  = (uint4*)(ws + 30400000);      // 38.4 MB
    int* rowptr = (int*)(ws + 68800000);           // NN+1 ints
    _Float16* h16   = (_Float16*)(ws + 69300000);  // 12.8 MB
    _Float16* agg16 = (_Float16*)(ws + 82100000);  // 12.8 MB
    float* sm   = (float*)(ws + 94900000);
    unsigned* Wc16 = (unsigned*)sm;  // 3*512 uints (edge weights f16)
    float* bc       = sm + 1536;     // 192
    float* scale    = sm + 1728;     // 64
    float* shift    = sm + 1792;     // 64
    float* bn_sum   = sm + 1856;     // 64
    float* bn_sumsq = sm + 1920;     // 64
    float* pooled   = sm + 1984;     // 32768
    float* ha       = sm + 34752;    // 32768
    float* hb       = sm + 67520;    // 32768
    int* bsum       = (int*)(sm + 100288);   // NB_SCAN ints
    int* bscan      = bsum + 512;
    v8h* Wpk        = (v8h*)(sm + 101376);   // 7*512*16 B (16B-aligned)

    const int* src = edge_index;
    const int* dst = edge_index + NE;

    const int mfma_blocks  = (NN/16 + 3) / 4;    // 1563
    const int edge_blocks  = (NE + 255) / 256;   // 4688
    const int agg_blocks   = (NN + 3) / 4;       // 25000

    prep_kernel<<<NL, 1024, 0, stream>>>(w_edge, b_edge, lin_w, lin_b, Wc16, bc);
    pack_w_kernel<<<7, 512, 0, stream>>>(w_node, mlp1_w, mlp2_w, Wpk);

    // h16 = f16( x @ w_node + b_node )
    mfma_gemm_kernel<false, false, false, false, false, true><<<mfma_blocks, 256, 0, stream>>>(
        x, nullptr, Wpk, b_node, nullptr, nullptr, nullptr, h16, nullptr, nullptr);

    // CSR build (per launch; edge_index is an input)
    hipMemsetAsync(counts, 0, NN * sizeof(int), stream);
    hist_kernel<<<edge_blocks, 256, 0, stream>>>(dst, counts);
    scan_reduce_kernel<<<NB_SCAN, 256, 0, stream>>>(counts, bsum);
    scan_partials_kernel<<<1, 512, 0, stream>>>(bsum, bscan);
    scan_final_kernel<<<NB_SCAN, 256, 0, stream>>>(counts, bscan, rowptr, next);
    scatter_kernel<<<edge_blocks, 256, 0, stream>>>(
        src, dst, edge_attr, next, csr_src, csr_ea);

    for (int l = 0; l < NL; ++l) {
        agg_kernel<<<agg_blocks, 256, 0, stream>>>(
            rowptr, csr_src, csr_ea, Wc16 + l*512, bc + l*64, h16, agg16);
        hipMemsetAsync(bn_sum, 0, 128 * sizeof(float), stream);
        // t = agg16 @ mlp1_w + b  (fp32 out) + BN stats
        mfma_gemm_kernel<true, false, false, true, true, false><<<mfma_blocks, 256, 0, stream>>>(
            nullptr, agg16, Wpk + (1+l)*512, mlp1_b + l*64, nullptr, nullptr,
            t, nullptr, bn_sum, bn_sumsq);
        bn_finalize_kernel<<<1, 64, 0, stream>>>(
            bn_sum, bn_sumsq, bn1_g + l*64, bn1_b + l*64, 1.0f / NN, scale, shift);
        // h16 = f16( relu( relu(bn(t)) @ mlp2_w + b ) )
        mfma_gemm_kernel<false, true, true, false, false, true><<<mfma_blocks, 256, 0, stream>>>(
            t, nullptr, Wpk + (4+l)*512, mlp2_b + l*64, scale, shift,
            nullptr, h16, nullptr, nullptr);
    }

    pool_kernel<<<NG, 256, 0, stream>>>(h16, batch, pooled);

    hipMemsetAsync(bn_sum, 0, 128 * sizeof(float), stream);
    gemm64_kernel<0, false, true><<<NG/64, 256, 0, stream>>>(
        pooled, fo1_w, fo1_b, nullptr, nullptr, ha, NG, bn_sum, bn_sumsq);
    bn_finalize_kernel<<<1, 64, 0, stream>>>(
        bn_sum, bn_sumsq, fo_bn1_g, fo_bn1_b, 1.0f / NG, scale, shift);
    hipMemsetAsync(bn_sum, 0, 128 * sizeof(float), stream);
    gemm64_kernel<2, false, true><<<NG/64, 256, 0, stream>>>(
        ha, fo2_w, fo2_b, scale, shift, hb, NG, bn_sum, bn_sumsq);
    bn_finalize_kernel<<<1, 64, 0, stream>>>(
        bn_sum, bn_sumsq, fo_bn2_g, fo_bn2_b, 1.0f / NG, scale, shift);
    head_final_kernel<<<(NG*NC + 255)/256, 256, 0, stream>>>(
        hb, scale, shift, fo3_w, fo3_b, out);
}